// Round 14
// baseline (35.318 us; speedup 1.0000x reference)
//
#include <hip/hip_runtime.h>
#include <math.h>

// ---- problem constants (fixed by setup_inputs) ----
#define NSPACE 16
#define SPN    1024
#define OPN    256
#define STRIDE 4          // SPN/OPN
#define CONV   16         // min(1024-256+1, 16)
#define KTOT   4096       // NSPACE*OPN
#define INC    32
#define OUTC   32
#define NB     27         // 3*3*3 basis
#define EPS_R  1e-8f

#define OFF_OUT 12288     // KTOT*3
#define OFF_RES 143360    // KTOT*3 + KTOT*OUTC

typedef float v2f __attribute__((ext_vector_type(2)));

// =============== DPP cross-lane helpers (no LDS pipe) ===============
#define UPDPP __builtin_amdgcn_update_dpp

// min over all 64 lanes, broadcast to all lanes via readlane(63)
__device__ __forceinline__ float wave_min64_bcast(float m) {
  int t;
  t = UPDPP(__float_as_int(m), __float_as_int(m), 0x111, 0xf, 0xf, false);
  m = fminf(m, __int_as_float(t));
  t = UPDPP(__float_as_int(m), __float_as_int(m), 0x112, 0xf, 0xf, false);
  m = fminf(m, __int_as_float(t));
  t = UPDPP(__float_as_int(m), __float_as_int(m), 0x114, 0xf, 0xf, false);
  m = fminf(m, __int_as_float(t));
  t = UPDPP(__float_as_int(m), __float_as_int(m), 0x118, 0xf, 0xf, false);
  m = fminf(m, __int_as_float(t));
  t = UPDPP(__float_as_int(m), __float_as_int(m), 0x142, 0xa, 0xf, false);
  m = fminf(m, __int_as_float(t));
  t = UPDPP(__float_as_int(m), __float_as_int(m), 0x143, 0xc, 0xf, false);
  m = fminf(m, __int_as_float(t));
  return __int_as_float(__builtin_amdgcn_readlane(__float_as_int(m), 63));
}

// sum over all 64 lanes, broadcast to all lanes
__device__ __forceinline__ float wave_sum64_bcast(float m) {
  int t;
  t = UPDPP(0, __float_as_int(m), 0x111, 0xf, 0xf, true); m += __int_as_float(t);
  t = UPDPP(0, __float_as_int(m), 0x112, 0xf, 0xf, true); m += __int_as_float(t);
  t = UPDPP(0, __float_as_int(m), 0x114, 0xf, 0xf, true); m += __int_as_float(t);
  t = UPDPP(0, __float_as_int(m), 0x118, 0xf, 0xf, true); m += __int_as_float(t);
  t = UPDPP(0, __float_as_int(m), 0x142, 0xa, 0xf, true); m += __int_as_float(t);
  t = UPDPP(0, __float_as_int(m), 0x143, 0xc, 0xf, true); m += __int_as_float(t);
  return __int_as_float(__builtin_amdgcn_readlane(__float_as_int(m), 63));
}

// sum within each 8-lane group; result valid in lanes 7 mod 8
__device__ __forceinline__ float group8_sum(float m) {
  int t;
  t = UPDPP(0, __float_as_int(m), 0x111, 0xf, 0xf, true); m += __int_as_float(t);
  t = UPDPP(0, __float_as_int(m), 0x112, 0xf, 0xf, true); m += __int_as_float(t);
  t = UPDPP(0, __float_as_int(m), 0x114, 0xf, 0xf, true); m += __int_as_float(t);
  return m;
}

// =============== LAPACK float32 clones (branch-faithful, ZERO arrays) =======

#define EIGH_Z_PARAMS                                                         \
  float &z00, float &z01, float &z02, float &z10, float &z11, float &z12,     \
  float &z20, float &z21, float &z22
#define EIGH_Z_ARGS z00, z01, z02, z10, z11, z12, z20, z21, z22

#define ROT01(c, s)                                              \
  { float _t;                                                    \
    _t = z01; z01 = (c) * _t - (s) * z00; z00 = (s) * _t + (c) * z00; \
    _t = z11; z11 = (c) * _t - (s) * z10; z10 = (s) * _t + (c) * z10; \
    _t = z21; z21 = (c) * _t - (s) * z20; z20 = (s) * _t + (c) * z20; }
#define ROT12(c, s)                                              \
  { float _t;                                                    \
    _t = z02; z02 = (c) * _t - (s) * z01; z01 = (s) * _t + (c) * z01; \
    _t = z12; z12 = (c) * _t - (s) * z11; z11 = (s) * _t + (c) * z11; \
    _t = z22; z22 = (c) * _t - (s) * z21; z21 = (s) * _t + (c) * z21; }
#define SWAP01 { float _t; _t = z00; z00 = z01; z01 = _t; _t = z10; z10 = z11; z11 = _t; _t = z20; z20 = z21; z21 = _t; }
#define SWAP02 { float _t; _t = z00; z00 = z02; z02 = _t; _t = z10; z10 = z12; z12 = _t; _t = z20; z20 = z22; z22 = _t; }
#define SWAP12 { float _t; _t = z01; z01 = z02; z02 = _t; _t = z11; z11 = z12; z12 = _t; _t = z21; z21 = z22; z22 = _t; }

__device__ __forceinline__ float f_sign(float a, float b) {
  return (b >= 0.0f) ? fabsf(a) : -fabsf(a);
}

__device__ __forceinline__ float slapy2(float x, float y) {
  float xa = fabsf(x), ya = fabsf(y);
  float w = fmaxf(xa, ya), zz = fminf(xa, ya);
  if (zz == 0.0f) return w;
  float q = zz / w;
  return w * __fsqrt_rn(1.0f + q * q);
}

__device__ __forceinline__ void slartg_(float f, float g, float* c, float* s, float* r) {
  const float safmin = 1.1754943508e-38f;
  const float safmax = 8.5070591730e+37f;
  const float rtmin  = 1.0842021725e-19f;
  const float rtmax  = 9.2233720369e+18f;
  float f1 = fabsf(f), g1 = fabsf(g);
  if (g == 0.0f) {
    *c = 1.0f; *s = 0.0f; *r = f;
  } else if (f == 0.0f) {
    *c = 0.0f; *s = (g >= 0.0f) ? 1.0f : -1.0f; *r = g1;
  } else if (f1 > rtmin && f1 < rtmax && g1 > rtmin && g1 < rtmax) {
    float d = __fsqrt_rn(f * f + g * g);
    *c = f1 / d;
    *r = (f >= 0.0f) ? d : -d;
    *s = g / (*r);
  } else {
    float u = fminf(safmax, fmaxf(safmin, fmaxf(f1, g1)));
    float fs = f / u, gs = g / u;
    float d = __fsqrt_rn(fs * fs + gs * gs);
    *c = fabsf(fs) / d;
    float rr = (f >= 0.0f) ? d : -d;
    *s = gs / rr;
    *r = rr * u;
  }
}

__device__ __forceinline__ void slaev2_(float a, float b, float c,
                                        float* rt1, float* rt2, float* cs1, float* sn1) {
  float sm = a + c;
  float df = a - c;
  float adf = fabsf(df);
  float tb = b + b;
  float ab = fabsf(tb);
  float acmx, acmn;
  if (fabsf(a) > fabsf(c)) { acmx = a; acmn = c; } else { acmx = c; acmn = a; }
  float rt;
  if (adf > ab)      { float q = ab / adf; rt = adf * __fsqrt_rn(1.0f + q * q); }
  else if (adf < ab) { float q = adf / ab; rt = ab  * __fsqrt_rn(1.0f + q * q); }
  else               { rt = ab * __fsqrt_rn(2.0f); }
  int sgn1;
  if (sm < 0.0f) {
    *rt1 = 0.5f * (sm - rt); sgn1 = -1;
    *rt2 = (acmx / *rt1) * acmn - (b / *rt1) * b;
  } else if (sm > 0.0f) {
    *rt1 = 0.5f * (sm + rt); sgn1 = 1;
    *rt2 = (acmx / *rt1) * acmn - (b / *rt1) * b;
  } else {
    *rt1 = 0.5f * rt; *rt2 = -0.5f * rt; sgn1 = 1;
  }
  float cs; int sgn2;
  if (df >= 0.0f) { cs = df + rt; sgn2 = 1; } else { cs = df - rt; sgn2 = -1; }
  float acs = fabsf(cs);
  if (acs > ab) {
    float ct = -tb / cs;
    *sn1 = 1.0f / __fsqrt_rn(1.0f + ct * ct);
    *cs1 = ct * (*sn1);
  } else {
    if (ab == 0.0f) { *cs1 = 1.0f; *sn1 = 0.0f; }
    else {
      float tn = -cs / tb;
      *cs1 = 1.0f / __fsqrt_rn(1.0f + tn * tn);
      *sn1 = tn * (*cs1);
    }
  }
  if (sgn1 == sgn2) { float tn = *cs1; *cs1 = -(*sn1); *sn1 = tn; }
}

__device__ __forceinline__ void steqr2_01(float& dA, float& eA, float& dB,
                                          bool ql, EIGH_Z_PARAMS) {
  const float eps2 = 3.5527136788e-15f, safmin = 1.1754943508e-38f;
  float tst = eA * eA;
  float thr = ql ? (eps2 * fabsf(dA)) * fabsf(dB) + safmin
                 : (eps2 * fabsf(dB)) * fabsf(dA) + safmin;
  if (tst <= thr) { eA = 0.0f; return; }
  float rt1, rt2, c, s;
  slaev2_(dA, eA, dB, &rt1, &rt2, &c, &s);
  ROT01(c, s);
  dA = rt1; dB = rt2; eA = 0.0f;
}

__device__ __forceinline__ void steqr2_12(float& dA, float& eA, float& dB,
                                          bool ql, EIGH_Z_PARAMS) {
  const float eps2 = 3.5527136788e-15f, safmin = 1.1754943508e-38f;
  float tst = eA * eA;
  float thr = ql ? (eps2 * fabsf(dA)) * fabsf(dB) + safmin
                 : (eps2 * fabsf(dB)) * fabsf(dA) + safmin;
  if (tst <= thr) { eA = 0.0f; return; }
  float rt1, rt2, c, s;
  slaev2_(dA, eA, dB, &rt1, &rt2, &c, &s);
  ROT12(c, s);
  dA = rt1; dB = rt2; eA = 0.0f;
}

__device__ __forceinline__ void steqr_ql3(float& d1, float& d2, float& d3,
                                          float& e1, float& e2, int& jtot,
                                          EIGH_Z_PARAMS) {
  const float eps2 = 3.5527136788e-15f, safmin = 1.1754943508e-38f;
  int l = 1;
  while (true) {
    if (l == 1) {
      if (e1 * e1 <= (eps2 * fabsf(d1)) * fabsf(d2) + safmin) { e1 = 0.0f; l = 2; continue; }
      if (e2 * e2 <= (eps2 * fabsf(d2)) * fabsf(d3) + safmin) {
        e2 = 0.0f;
        float rt1, rt2, c, s;
        slaev2_(d1, e1, d2, &rt1, &rt2, &c, &s);
        ROT01(c, s);
        d1 = rt1; d2 = rt2; e1 = 0.0f;
        l = 3; continue;
      }
      if (jtot == 90) return;
      jtot++;
      float p = d1;
      float g = (d2 - p) / (2.0f * e1);
      float r = slapy2(g, 1.0f);
      g = d3 - p + (e1 / (g + f_sign(r, g)));
      float s = 1.0f, c = 1.0f; p = 0.0f;
      float f, b, wc1, wc2, ws1, ws2;
      f = s * e2; b = c * e2;
      slartg_(g, f, &c, &s, &r);
      g = d3 - p;
      r = (d2 - g) * s + 2.0f * c * b;
      p = s * r;
      d3 = g + p;
      g = c * r - b;
      wc2 = c; ws2 = -s;
      f = s * e1; b = c * e1;
      slartg_(g, f, &c, &s, &r);
      e2 = r;
      g = d2 - p;
      r = (d1 - g) * s + 2.0f * c * b;
      p = s * r;
      d2 = g + p;
      g = c * r - b;
      wc1 = c; ws1 = -s;
      if (wc2 != 1.0f || ws2 != 0.0f) ROT12(wc2, ws2);
      if (wc1 != 1.0f || ws1 != 0.0f) ROT01(wc1, ws1);
      d1 = d1 - p;
      e1 = g;
      continue;
    }
    if (l == 2) {
      if (e2 * e2 <= (eps2 * fabsf(d2)) * fabsf(d3) + safmin) { e2 = 0.0f; l = 3; continue; }
      float rt1, rt2, c, s;
      slaev2_(d2, e2, d3, &rt1, &rt2, &c, &s);
      ROT12(c, s);
      d2 = rt1; d3 = rt2; e2 = 0.0f;
      return;
    }
    return;
  }
}

__device__ __forceinline__ void steqr_qr3(float& d1, float& d2, float& d3,
                                          float& e1, float& e2, int& jtot,
                                          EIGH_Z_PARAMS) {
  const float eps2 = 3.5527136788e-15f, safmin = 1.1754943508e-38f;
  int l = 3;
  while (true) {
    if (l == 3) {
      if (e2 * e2 <= (eps2 * fabsf(d3)) * fabsf(d2) + safmin) { e2 = 0.0f; l = 2; continue; }
      if (e1 * e1 <= (eps2 * fabsf(d2)) * fabsf(d1) + safmin) {
        e1 = 0.0f;
        float rt1, rt2, c, s;
        slaev2_(d2, e2, d3, &rt1, &rt2, &c, &s);
        ROT12(c, s);
        d2 = rt1; d3 = rt2; e2 = 0.0f;
        l = 1; continue;
      }
      if (jtot == 90) return;
      jtot++;
      float p = d3;
      float g = (d2 - p) / (2.0f * e2);
      float r = slapy2(g, 1.0f);
      g = d1 - p + (e2 / (g + f_sign(r, g)));
      float s = 1.0f, c = 1.0f; p = 0.0f;
      float f, b, wc1, wc2, ws1, ws2;
      f = s * e1; b = c * e1;
      slartg_(g, f, &c, &s, &r);
      g = d1 - p;
      r = (d2 - g) * s + 2.0f * c * b;
      p = s * r;
      d1 = g + p;
      g = c * r - b;
      wc1 = c; ws1 = s;
      f = s * e2; b = c * e2;
      slartg_(g, f, &c, &s, &r);
      e1 = r;
      g = d2 - p;
      r = (d3 - g) * s + 2.0f * c * b;
      p = s * r;
      d2 = g + p;
      g = c * r - b;
      wc2 = c; ws2 = s;
      if (wc1 != 1.0f || ws1 != 0.0f) ROT01(wc1, ws1);
      if (wc2 != 1.0f || ws2 != 0.0f) ROT12(wc2, ws2);
      d3 = d3 - p;
      e2 = g;
      continue;
    }
    if (l == 2) {
      if (e1 * e1 <= (eps2 * fabsf(d2)) * fabsf(d1) + safmin) { e1 = 0.0f; l = 1; continue; }
      float rt1, rt2, c, s;
      slaev2_(d1, e1, d2, &rt1, &rt2, &c, &s);
      ROT01(c, s);
      d1 = rt1; d2 = rt2; e1 = 0.0f;
      return;
    }
    return;
  }
}

__device__ __forceinline__ void ssteqr3s(float& d1, float& d2, float& d3,
                                         float& e1, float& e2, EIGH_Z_PARAMS) {
  const float eps    = 5.9604644775e-08f;
  const float ssfmax = 3.0744573457e+18f;
  const float ssfmin = 3.0517578125e-05f;
  int jtot = 0;
  int m;
  {
    float tst = fabsf(e1);
    if (tst == 0.0f) m = 1;
    else if (tst <= (__fsqrt_rn(fabsf(d1)) * __fsqrt_rn(fabsf(d2))) * eps) { e1 = 0.0f; m = 1; }
    else {
      tst = fabsf(e2);
      if (tst == 0.0f) m = 2;
      else if (tst <= (__fsqrt_rn(fabsf(d2)) * __fsqrt_rn(fabsf(d3))) * eps) { e2 = 0.0f; m = 2; }
      else m = 3;
    }
  }
  if (m == 3) {
    float anorm = fmaxf(fmaxf(fabsf(d1), fabsf(d2)), fabsf(d3));
    anorm = fmaxf(anorm, fmaxf(fabsf(e1), fabsf(e2)));
    if (anorm != 0.0f) {
      int iscale = 0; float mul;
      if (anorm > ssfmax) {
        iscale = 1; mul = ssfmax / anorm;
        d1 *= mul; d2 *= mul; d3 *= mul; e1 *= mul; e2 *= mul;
      } else if (anorm < ssfmin) {
        iscale = 2; mul = ssfmin / anorm;
        d1 *= mul; d2 *= mul; d3 *= mul; e1 *= mul; e2 *= mul;
      }
      if (fabsf(d3) < fabsf(d1)) steqr_qr3(d1, d2, d3, e1, e2, jtot, EIGH_Z_ARGS);
      else                       steqr_ql3(d1, d2, d3, e1, e2, jtot, EIGH_Z_ARGS);
      if (iscale == 1) {
        mul = anorm / ssfmax;
        d1 *= mul; d2 *= mul; d3 *= mul; e1 *= mul; e2 *= mul;
      } else if (iscale == 2) {
        mul = anorm / ssfmin;
        d1 *= mul; d2 *= mul; d3 *= mul; e1 *= mul; e2 *= mul;
      }
    }
  } else if (m == 2) {
    float anorm = fmaxf(fmaxf(fabsf(d1), fabsf(d2)), fabsf(e1));
    if (anorm != 0.0f) {
      int iscale = 0; float mul;
      if (anorm > ssfmax) { iscale = 1; mul = ssfmax / anorm; d1 *= mul; d2 *= mul; e1 *= mul; }
      else if (anorm < ssfmin) { iscale = 2; mul = ssfmin / anorm; d1 *= mul; d2 *= mul; e1 *= mul; }
      steqr2_01(d1, e1, d2, !(fabsf(d2) < fabsf(d1)), EIGH_Z_ARGS);
      if (iscale == 1) { mul = anorm / ssfmax; d1 *= mul; d2 *= mul; e1 *= mul; }
      else if (iscale == 2) { mul = anorm / ssfmin; d1 *= mul; d2 *= mul; e1 *= mul; }
    }
  } else {
    int m2;
    float tst = fabsf(e2);
    if (tst == 0.0f) m2 = 2;
    else if (tst <= (__fsqrt_rn(fabsf(d2)) * __fsqrt_rn(fabsf(d3))) * eps) { e2 = 0.0f; m2 = 2; }
    else m2 = 3;
    if (m2 == 3) {
      float anorm = fmaxf(fmaxf(fabsf(d2), fabsf(d3)), fabsf(e2));
      if (anorm != 0.0f) {
        int iscale = 0; float mul;
        if (anorm > ssfmax) { iscale = 1; mul = ssfmax / anorm; d2 *= mul; d3 *= mul; e2 *= mul; }
        else if (anorm < ssfmin) { iscale = 2; mul = ssfmin / anorm; d2 *= mul; d3 *= mul; e2 *= mul; }
        steqr2_12(d2, e2, d3, !(fabsf(d3) < fabsf(d2)), EIGH_Z_ARGS);
        if (iscale == 1) { mul = anorm / ssfmax; d2 *= mul; d3 *= mul; e2 *= mul; }
        else if (iscale == 2) { mul = anorm / ssfmin; d2 *= mul; d3 *= mul; e2 *= mul; }
      }
    }
  }
  {
    int k = 1; float p = d1;
    if (d2 < p) { k = 2; p = d2; }
    if (d3 < p) { k = 3; p = d3; }
    if (k == 2)      { d2 = d1; d1 = p; SWAP01; }
    else if (k == 3) { d3 = d1; d1 = p; SWAP02; }
    if (d3 < d2) { p = d3; d3 = d2; d2 = p; SWAP12; }
  }
}

__device__ __forceinline__ void eigh3(float a11, float a21, float a31,
                                      float a22, float a32, float a33,
                                      EIGH_Z_PARAMS) {
  float tau1 = 0.0f, v3 = 0.0f, e1;
  float xnorm = fabsf(a31);
  if (xnorm == 0.0f) {
    tau1 = 0.0f;
    e1 = a21;
    v3 = 0.0f;
  } else {
    float beta = -f_sign(slapy2(a21, xnorm), a21);
    tau1 = (beta - a21) / beta;
    v3 = a31 / (a21 - beta);
    e1 = beta;
  }
  if (tau1 != 0.0f) {
    float x1 = tau1 * (a22 + a32 * v3);
    float x2 = tau1 * (a32 + a33 * v3);
    float alpha = -0.5f * tau1 * (x1 + x2 * v3);
    float w1 = x1 + alpha;
    float w2 = x2 + alpha * v3;
    a22 = a22 - w1 - w1;
    a32 = a32 - v3 * w1 - w2;
    a33 = a33 - v3 * w2 - w2 * v3;
  }
  float d1 = a11, d2 = a22, d3 = a33, e2 = a32;
  z00 = 1.0f; z01 = 0.0f; z02 = 0.0f;
  z10 = 0.0f; z11 = 1.0f; z12 = 0.0f;
  z20 = 0.0f; z21 = 0.0f; z22 = 1.0f;
  ssteqr3s(d1, d2, d3, e1, e2, EIGH_Z_ARGS);
  if (tau1 != 0.0f) {
    float tt;
    tt = z10 + v3 * z20; z10 -= tau1 * tt; z20 -= tau1 * tt * v3;
    tt = z11 + v3 * z21; z11 -= tau1 * tt; z21 -= tau1 * tt * v3;
    tt = z12 + v3 * z22; z12 -= tau1 * tt; z22 -= tau1 * tt * v3;
  }
}

// =============================== fused kernel ===============================
// 1 wave per center, 4 centers (waves) per block, grid = KTOT/4 blocks.
// All 4 waves share one space -> stage its pos tile (12KB) into LDS once,
// aliased with the G4 buffer (pos dead before G4 is written; barrier between).

#define CE(i, j)                                                  \
  {                                                               \
    unsigned long long ta = K[i], tb = K[j];                      \
    bool sw = tb < ta;                                            \
    K[i] = sw ? tb : ta;                                          \
    K[j] = sw ? ta : tb;                                          \
  }

#define RFL(x) __int_as_float(__builtin_amdgcn_readfirstlane(__float_as_int(x)))

__global__ __launch_bounds__(256, 4) void dcconv_fused(
    const float* __restrict__ pos, const float* __restrict__ chan,
    const float* __restrict__ coeff, const float* __restrict__ bias,
    float* __restrict__ out) {
  const int t    = threadIdx.x;
  const int wv   = t >> 6;                 // 0..3 : center slot in block
  const int lane = t & 63;
  const int kglob = blockIdx.x * 4 + wv;   // global center id 0..4095
  const int sp   = kglob >> 8;             // space id (same for all 4 waves)
  const int ci   = kglob & 255;            // center within space
  const int base = sp * SPN;

  __shared__ __align__(16) float basis_sh[4][CONV][28];   // col 27 = 0
  __shared__ __align__(16) float feat_sh[4][CONV][INC];
  // union: [0..12287B) = pos tile (phases 1-2a); then G4 flat [4][864]
  __shared__ __align__(16) float u_sh[4 * INC * NB];      // 13824B

  // ---- phase 0: stage this block's space pos tile into LDS (coalesced) ----
  {
    const float4* src = (const float4*)(pos + base * 3);  // 768 float4s
    float4* dst = (float4*)u_sh;
#pragma unroll
    for (int k = 0; k < 3; ++k) dst[t + 256 * k] = src[t + 256 * k];
  }
  __syncthreads();
  const float* posL = u_sh;

  // ---- phase 1: d2 for all 1024 points (reads LDS; stride-3 dwords,
  //      3 coprime 32 -> conflict-free) ----
  const int cloc = ci * STRIDE;
  const float cx = posL[cloc * 3 + 0];
  const float cy = posL[cloc * 3 + 1];
  const float cz = posL[cloc * 3 + 2];

  unsigned long long K[16];
#pragma unroll
  for (int u = 0; u < 16; ++u) {
    const int j = u * 64 + lane;
    const float px = posL[j * 3 + 0];
    const float py = posL[j * 3 + 1];
    const float pz = posL[j * 3 + 2];
    float dx = __fsub_rn(cx, px), dy = __fsub_rn(cy, py), dz = __fsub_rn(cz, pz);
    float d2 = __fadd_rn(__fadd_rn(__fmul_rn(dx, dx), __fmul_rn(dy, dy)),
                         __fmul_rn(dz, dz));
    K[u] = (((unsigned long long)__float_as_uint(d2)) << 32) | (unsigned)j;
  }

  // ---- phase 1b: per-lane ascending sort (Batcher odd-even merge, 63 CEs) --
  CE(0, 1) CE(2, 3) CE(4, 5) CE(6, 7) CE(8, 9) CE(10, 11) CE(12, 13) CE(14, 15)
  CE(0, 2) CE(1, 3) CE(4, 6) CE(5, 7) CE(8, 10) CE(9, 11) CE(12, 14) CE(13, 15)
  CE(1, 2) CE(5, 6) CE(9, 10) CE(13, 14)
  CE(0, 4) CE(1, 5) CE(2, 6) CE(3, 7) CE(8, 12) CE(9, 13) CE(10, 14) CE(11, 15)
  CE(2, 4) CE(3, 5) CE(10, 12) CE(11, 13)
  CE(1, 2) CE(3, 4) CE(5, 6) CE(9, 10) CE(11, 12) CE(13, 14)
  CE(0, 8) CE(1, 9) CE(2, 10) CE(3, 11) CE(4, 12) CE(5, 13) CE(6, 14) CE(7, 15)
  CE(4, 8) CE(5, 9) CE(6, 10) CE(7, 11)
  CE(2, 4) CE(3, 5) CE(6, 8) CE(7, 9) CE(10, 12) CE(11, 13)
  CE(1, 2) CE(3, 4) CE(5, 6) CE(7, 8) CE(9, 10) CE(11, 12) CE(13, 14)

  // ---- phase 1c: 16 rounds of DPP wave-min + pop (set-exact selection) ----
  int myloc = cloc;   // lane c<16 will own neighbor c's LOCAL index
#pragma unroll 1
  for (int it = 0; it < CONV; ++it) {
    const float f0 = __uint_as_float((unsigned)(K[0] >> 32));  // NaN if empty
    const float m = wave_min64_bcast(f0);
    const unsigned long long msk = __ballot(f0 == m);
    const int wl = (int)__builtin_ctzll(msk);
    const int widx = __builtin_amdgcn_readlane((int)(unsigned)(K[0] & 0xffffffffu), wl);
    if (lane == it) myloc = widx;
    const bool on = (lane == wl);
#pragma unroll
    for (int u = 0; u < 15; ++u) K[u] = on ? K[u + 1] : K[u];
    K[15] = on ? ~0ull : K[15];
  }

  // ---- phase 2a: neighbor positions from LDS (lanes 0..15) ----
  float nx = 0.0f, ny = 0.0f, nz = 0.0f;
  if (lane < CONV) {
    const float* pp = posL + myloc * 3;
    nx = pp[0]; ny = pp[1]; nz = pp[2];
  }

  // ---- phase 3a (hoisted loads): feat values into named scalars ----
  const int hc = lane >> 5;          // 0/1
  const int ifeat = lane & 31;
  float fv0, fv1, fv2, fv3, fv4, fv5, fv6, fv7;
  {
    int g;
    g = base + __shfl(myloc,  0 + hc); fv0 = chan[g * INC + ifeat];
    g = base + __shfl(myloc,  2 + hc); fv1 = chan[g * INC + ifeat];
    g = base + __shfl(myloc,  4 + hc); fv2 = chan[g * INC + ifeat];
    g = base + __shfl(myloc,  6 + hc); fv3 = chan[g * INC + ifeat];
    g = base + __shfl(myloc,  8 + hc); fv4 = chan[g * INC + ifeat];
    g = base + __shfl(myloc, 10 + hc); fv5 = chan[g * INC + ifeat];
    g = base + __shfl(myloc, 12 + hc); fv6 = chan[g * INC + ifeat];
    g = base + __shfl(myloc, 14 + hc); fv7 = chan[g * INC + ifeat];
  }

  // ---- phase 2b: mean + cov via DPP sums (lanes>=16 contribute 0) ----
  const float mx = wave_sum64_bcast(nx) * 0.0625f;
  const float my = wave_sum64_bcast(ny) * 0.0625f;
  const float mz = wave_sum64_bcast(nz) * 0.0625f;
  if (lane == 0) {
    out[kglob * 3 + 0] = mx; out[kglob * 3 + 1] = my; out[kglob * 3 + 2] = mz;
  }
  const float lx = nx - mx, ly = ny - my, lz = nz - mz;   // valid lanes<16
  const float lxm = (lane < CONV) ? lx : 0.0f;
  const float lym = (lane < CONV) ? ly : 0.0f;
  const float lzm = (lane < CONV) ? lz : 0.0f;
  const float inv = 1.0f / (float)CONV;
  const float c00 = wave_sum64_bcast(lxm * lxm) * inv;
  const float c10 = wave_sum64_bcast(lym * lxm) * inv;
  const float c20 = wave_sum64_bcast(lzm * lxm) * inv;
  const float c11 = wave_sum64_bcast(lym * lym) * inv;
  const float c21 = wave_sum64_bcast(lzm * lym) * inv;
  const float c22 = wave_sum64_bcast(lzm * lzm) * inv;

  // ---- phase 2c: eigh on lane 0 ONLY, then readfirstlane broadcast of V ----
  float V00 = 0, V01 = 0, V02 = 0, V10 = 0, V11 = 0, V12 = 0,
        V20 = 0, V21 = 0, V22 = 0;
  if (lane == 0) {
    eigh3(c00, c10, c20, c11, c21, c22,
          V00, V01, V02, V10, V11, V12, V20, V21, V22);
  }
  V00 = RFL(V00); V01 = RFL(V01); V02 = RFL(V02);
  V10 = RFL(V10); V11 = RFL(V11); V12 = RFL(V12);
  V20 = RFL(V20); V21 = RFL(V21); V22 = RFL(V22);

  // ---- phase 2d: spherical coords + basis (lanes 0..15 of each wave) ----
  if (lane < CONV) {
    float x = lx * V00 + ly * V10 + lz * V20;
    float y = lx * V01 + ly * V11 + lz * V21;
    float z = lx * V02 + ly * V12 + lz * V22;
    float r = __fsqrt_rn(x * x + y * y + z * z + EPS_R);
    float ct = fminf(fmaxf(z / r, -1.0f), 1.0f);
    float theta = acosf(ct);
    float phi = atan2f(y, x);
    const float r1 = r, r2 = r * r;
    const float t1 = theta, t2 = theta * theta;
    const float p1 = phi, p2 = phi * phi;
    float4* bp = (float4*)(&basis_sh[wv][lane][0]);
    bp[0] = make_float4(1.0f,      p1,        p2,        t1);
    bp[1] = make_float4(t1 * p1,   t1 * p2,   t2,        t2 * p1);
    bp[2] = make_float4(t2 * p2,   r1,        r1 * p1,   r1 * p2);
    bp[3] = make_float4(r1 * t1,   r1 * t1 * p1, r1 * t1 * p2, r1 * t2);
    bp[4] = make_float4(r1 * t2 * p1, r1 * t2 * p2, r2,  r2 * p1);
    bp[5] = make_float4(r2 * p2,   r2 * t1,   r2 * t1 * p1, r2 * t1 * p2);
    bp[6] = make_float4(r2 * t2,   r2 * t2 * p1, r2 * t2 * p2, 0.0f);
  }

  // ---- phase 3b: feat -> LDS + resnet sum ----
  feat_sh[wv][ 0 + hc][ifeat] = fv0;
  feat_sh[wv][ 2 + hc][ifeat] = fv1;
  feat_sh[wv][ 4 + hc][ifeat] = fv2;
  feat_sh[wv][ 6 + hc][ifeat] = fv3;
  feat_sh[wv][ 8 + hc][ifeat] = fv4;
  feat_sh[wv][10 + hc][ifeat] = fv5;
  feat_sh[wv][12 + hc][ifeat] = fv6;
  feat_sh[wv][14 + hc][ifeat] = fv7;
  float s_loc = ((fv0 + fv1) + (fv2 + fv3)) + ((fv4 + fv5) + (fv6 + fv7));
  const float sres = wave_sum64_bcast(s_loc);
  if (lane < OUTC) out[OFF_RES + kglob * OUTC + lane] = sres;

  __syncthreads();   // pos tile dead in ALL waves -> u_sh may be reused as G4

  // ---- phase 4: G[i*27+j] = sum_c feat[c][i] * basis[c][j]  (packed f32,
  //      written into u_sh (now the flat G4 buffer)) ----
  {
    const int gi = lane >> 1;
    const int jh = lane & 1;
    const int jr0 = jh ? 12 : 0;       // 16B-aligned read start
    v2f a2[8];
#pragma unroll
    for (int q = 0; q < 8; ++q) a2[q] = (v2f)(0.0f);
#pragma unroll
    for (int c = 0; c < CONV; ++c) {
      const float f = feat_sh[wv][c][gi];
      const v2f f2 = (v2f)(f);
      const float4* bp = (const float4*)(&basis_sh[wv][c][jr0]);
#pragma unroll
      for (int q = 0; q < 4; ++q) {
        const float4 v4 = bp[q];
        v2f blo; blo.x = v4.x; blo.y = v4.y;
        v2f bhi; bhi.x = v4.z; bhi.y = v4.w;
        a2[2 * q + 0] += f2 * blo;
        a2[2 * q + 1] += f2 * bhi;
      }
    }
    float* gq = &u_sh[wv * (INC * NB) + gi * NB];
    if (jh == 0) {   // j 0..13 from a2[0..6]
#pragma unroll
      for (int jj = 0; jj < 14; ++jj)
        gq[jj] = (jj & 1) ? a2[jj >> 1].y : a2[jj >> 1].x;
    } else {         // j 14..26 from a2[1..7] (m = j-12 in 2..14)
#pragma unroll
      for (int jj = 14; jj < 27; ++jj) {
        const int m = jj - 12;
        gq[jj] = (m & 1) ? a2[m >> 1].y : a2[m >> 1].x;
      }
    }
  }

  __syncthreads();   // all four centers' flat G visible

  // ---- phase 5 (coalesced): out[o][c] = sum_ij coeff[o][ij] * G[c][ij] ----
  {
    const int o = t >> 3;          // 0..31
    const int q = t & 7;           // 0..7
    const float4* arow = (const float4*)(coeff + o * (INC * NB));
    const float4* g0 = (const float4*)(&u_sh[0 * INC * NB]);
    const float4* g1 = (const float4*)(&u_sh[1 * INC * NB]);
    const float4* g2 = (const float4*)(&u_sh[2 * INC * NB]);
    const float4* g3 = (const float4*)(&u_sh[3 * INC * NB]);
    v2f ac0 = (v2f)(0.0f), ac1 = (v2f)(0.0f), ac2 = (v2f)(0.0f), ac3 = (v2f)(0.0f);
#pragma unroll 3
    for (int k = 0; k < 27; ++k) {
      const int f4 = k * 8 + q;
      const float4 A = arow[f4];
      v2f Alo; Alo.x = A.x; Alo.y = A.y;
      v2f Ahi; Ahi.x = A.z; Ahi.y = A.w;
      float4 Gv; v2f Glo, Ghi;
      Gv = g0[f4];
      Glo.x = Gv.x; Glo.y = Gv.y; Ghi.x = Gv.z; Ghi.y = Gv.w;
      ac0 += Alo * Glo; ac0 += Ahi * Ghi;
      Gv = g1[f4];
      Glo.x = Gv.x; Glo.y = Gv.y; Ghi.x = Gv.z; Ghi.y = Gv.w;
      ac1 += Alo * Glo; ac1 += Ahi * Ghi;
      Gv = g2[f4];
      Glo.x = Gv.x; Glo.y = Gv.y; Ghi.x = Gv.z; Ghi.y = Gv.w;
      ac2 += Alo * Glo; ac2 += Ahi * Ghi;
      Gv = g3[f4];
      Glo.x = Gv.x; Glo.y = Gv.y; Ghi.x = Gv.z; Ghi.y = Gv.w;
      ac3 += Alo * Glo; ac3 += Ahi * Ghi;
    }
    float s0 = ac0.x + ac0.y;
    float s1 = ac1.x + ac1.y;
    float s2 = ac2.x + ac2.y;
    float s3 = ac3.x + ac3.y;
    s0 = group8_sum(s0); s1 = group8_sum(s1);
    s2 = group8_sum(s2); s3 = group8_sum(s3);
    if (q == 7) {
      const float b = bias[o];
      const int kb = blockIdx.x * 4;
      out[OFF_OUT + (kb + 0) * OUTC + o] = s0 + b;
      out[OFF_OUT + (kb + 1) * OUTC + o] = s1 + b;
      out[OFF_OUT + (kb + 2) * OUTC + o] = s2 + b;
      out[OFF_OUT + (kb + 3) * OUTC + o] = s3 + b;
    }
  }
}

extern "C" void kernel_launch(void* const* d_in, const int* in_sizes, int n_in,
                              void* d_out, int out_size, void* d_ws, size_t ws_size,
                              hipStream_t stream) {
  const float* pos   = (const float*)d_in[0];
  const float* chan  = (const float*)d_in[1];
  // d_in[2]=space_points_num, d_in[3]=outpoint_num: fixed (1024, 256) per setup
  const float* coeff = (const float*)d_in[4];
  const float* bias  = (const float*)d_in[5];
  float* out = (float*)d_out;
  dcconv_fused<<<dim3(KTOT / 4), dim3(256), 0, stream>>>(pos, chan, coeff, bias, out);
}

// Round 15
// 33.588 us; speedup vs baseline: 1.0515x; 1.0515x over previous
//
#include <hip/hip_runtime.h>
#include <math.h>

// ---- problem constants (fixed by setup_inputs) ----
#define NSPACE 16
#define SPN    1024
#define OPN    256
#define STRIDE 4          // SPN/OPN
#define CONV   16         // min(1024-256+1, 16)
#define KTOT   4096       // NSPACE*OPN
#define INC    32
#define OUTC   32
#define NB     27         // 3*3*3 basis
#define EPS_R  1e-8f

#define OFF_OUT 12288     // KTOT*3
#define OFF_RES 143360    // KTOT*3 + KTOT*OUTC

typedef float v2f __attribute__((ext_vector_type(2)));

// =============== DPP cross-lane helpers (no LDS pipe) ===============
#define UPDPP __builtin_amdgcn_update_dpp

// min over all 64 lanes, broadcast to all lanes via readlane(63)
__device__ __forceinline__ float wave_min64_bcast(float m) {
  int t;
  t = UPDPP(__float_as_int(m), __float_as_int(m), 0x111, 0xf, 0xf, false);
  m = fminf(m, __int_as_float(t));
  t = UPDPP(__float_as_int(m), __float_as_int(m), 0x112, 0xf, 0xf, false);
  m = fminf(m, __int_as_float(t));
  t = UPDPP(__float_as_int(m), __float_as_int(m), 0x114, 0xf, 0xf, false);
  m = fminf(m, __int_as_float(t));
  t = UPDPP(__float_as_int(m), __float_as_int(m), 0x118, 0xf, 0xf, false);
  m = fminf(m, __int_as_float(t));
  t = UPDPP(__float_as_int(m), __float_as_int(m), 0x142, 0xa, 0xf, false);
  m = fminf(m, __int_as_float(t));
  t = UPDPP(__float_as_int(m), __float_as_int(m), 0x143, 0xc, 0xf, false);
  m = fminf(m, __int_as_float(t));
  return __int_as_float(__builtin_amdgcn_readlane(__float_as_int(m), 63));
}

// sum over all 64 lanes, broadcast to all lanes
__device__ __forceinline__ float wave_sum64_bcast(float m) {
  int t;
  t = UPDPP(0, __float_as_int(m), 0x111, 0xf, 0xf, true); m += __int_as_float(t);
  t = UPDPP(0, __float_as_int(m), 0x112, 0xf, 0xf, true); m += __int_as_float(t);
  t = UPDPP(0, __float_as_int(m), 0x114, 0xf, 0xf, true); m += __int_as_float(t);
  t = UPDPP(0, __float_as_int(m), 0x118, 0xf, 0xf, true); m += __int_as_float(t);
  t = UPDPP(0, __float_as_int(m), 0x142, 0xa, 0xf, true); m += __int_as_float(t);
  t = UPDPP(0, __float_as_int(m), 0x143, 0xc, 0xf, true); m += __int_as_float(t);
  return __int_as_float(__builtin_amdgcn_readlane(__float_as_int(m), 63));
}

// sum within each 8-lane group; result valid in lanes 7 mod 8
__device__ __forceinline__ float group8_sum(float m) {
  int t;
  t = UPDPP(0, __float_as_int(m), 0x111, 0xf, 0xf, true); m += __int_as_float(t);
  t = UPDPP(0, __float_as_int(m), 0x112, 0xf, 0xf, true); m += __int_as_float(t);
  t = UPDPP(0, __float_as_int(m), 0x114, 0xf, 0xf, true); m += __int_as_float(t);
  return m;
}

// =============== LAPACK float32 clones (branch-faithful, ZERO arrays) =======

#define EIGH_Z_PARAMS                                                         \
  float &z00, float &z01, float &z02, float &z10, float &z11, float &z12,     \
  float &z20, float &z21, float &z22
#define EIGH_Z_ARGS z00, z01, z02, z10, z11, z12, z20, z21, z22

#define ROT01(c, s)                                              \
  { float _t;                                                    \
    _t = z01; z01 = (c) * _t - (s) * z00; z00 = (s) * _t + (c) * z00; \
    _t = z11; z11 = (c) * _t - (s) * z10; z10 = (s) * _t + (c) * z10; \
    _t = z21; z21 = (c) * _t - (s) * z20; z20 = (s) * _t + (c) * z20; }
#define ROT12(c, s)                                              \
  { float _t;                                                    \
    _t = z02; z02 = (c) * _t - (s) * z01; z01 = (s) * _t + (c) * z01; \
    _t = z12; z12 = (c) * _t - (s) * z11; z11 = (s) * _t + (c) * z11; \
    _t = z22; z22 = (c) * _t - (s) * z21; z21 = (s) * _t + (c) * z21; }
#define SWAP01 { float _t; _t = z00; z00 = z01; z01 = _t; _t = z10; z10 = z11; z11 = _t; _t = z20; z20 = z21; z21 = _t; }
#define SWAP02 { float _t; _t = z00; z00 = z02; z02 = _t; _t = z10; z10 = z12; z12 = _t; _t = z20; z20 = z22; z22 = _t; }
#define SWAP12 { float _t; _t = z01; z01 = z02; z02 = _t; _t = z11; z11 = z12; z12 = _t; _t = z21; z21 = z22; z22 = _t; }

__device__ __forceinline__ float f_sign(float a, float b) {
  return (b >= 0.0f) ? fabsf(a) : -fabsf(a);
}

__device__ __forceinline__ float slapy2(float x, float y) {
  float xa = fabsf(x), ya = fabsf(y);
  float w = fmaxf(xa, ya), zz = fminf(xa, ya);
  if (zz == 0.0f) return w;
  float q = zz / w;
  return w * __fsqrt_rn(1.0f + q * q);
}

__device__ __forceinline__ void slartg_(float f, float g, float* c, float* s, float* r) {
  const float safmin = 1.1754943508e-38f;
  const float safmax = 8.5070591730e+37f;
  const float rtmin  = 1.0842021725e-19f;
  const float rtmax  = 9.2233720369e+18f;
  float f1 = fabsf(f), g1 = fabsf(g);
  if (g == 0.0f) {
    *c = 1.0f; *s = 0.0f; *r = f;
  } else if (f == 0.0f) {
    *c = 0.0f; *s = (g >= 0.0f) ? 1.0f : -1.0f; *r = g1;
  } else if (f1 > rtmin && f1 < rtmax && g1 > rtmin && g1 < rtmax) {
    float d = __fsqrt_rn(f * f + g * g);
    *c = f1 / d;
    *r = (f >= 0.0f) ? d : -d;
    *s = g / (*r);
  } else {
    float u = fminf(safmax, fmaxf(safmin, fmaxf(f1, g1)));
    float fs = f / u, gs = g / u;
    float d = __fsqrt_rn(fs * fs + gs * gs);
    *c = fabsf(fs) / d;
    float rr = (f >= 0.0f) ? d : -d;
    *s = gs / rr;
    *r = rr * u;
  }
}

__device__ __forceinline__ void slaev2_(float a, float b, float c,
                                        float* rt1, float* rt2, float* cs1, float* sn1) {
  float sm = a + c;
  float df = a - c;
  float adf = fabsf(df);
  float tb = b + b;
  float ab = fabsf(tb);
  float acmx, acmn;
  if (fabsf(a) > fabsf(c)) { acmx = a; acmn = c; } else { acmx = c; acmn = a; }
  float rt;
  if (adf > ab)      { float q = ab / adf; rt = adf * __fsqrt_rn(1.0f + q * q); }
  else if (adf < ab) { float q = adf / ab; rt = ab  * __fsqrt_rn(1.0f + q * q); }
  else               { rt = ab * __fsqrt_rn(2.0f); }
  int sgn1;
  if (sm < 0.0f) {
    *rt1 = 0.5f * (sm - rt); sgn1 = -1;
    *rt2 = (acmx / *rt1) * acmn - (b / *rt1) * b;
  } else if (sm > 0.0f) {
    *rt1 = 0.5f * (sm + rt); sgn1 = 1;
    *rt2 = (acmx / *rt1) * acmn - (b / *rt1) * b;
  } else {
    *rt1 = 0.5f * rt; *rt2 = -0.5f * rt; sgn1 = 1;
  }
  float cs; int sgn2;
  if (df >= 0.0f) { cs = df + rt; sgn2 = 1; } else { cs = df - rt; sgn2 = -1; }
  float acs = fabsf(cs);
  if (acs > ab) {
    float ct = -tb / cs;
    *sn1 = 1.0f / __fsqrt_rn(1.0f + ct * ct);
    *cs1 = ct * (*sn1);
  } else {
    if (ab == 0.0f) { *cs1 = 1.0f; *sn1 = 0.0f; }
    else {
      float tn = -cs / tb;
      *cs1 = 1.0f / __fsqrt_rn(1.0f + tn * tn);
      *sn1 = tn * (*cs1);
    }
  }
  if (sgn1 == sgn2) { float tn = *cs1; *cs1 = -(*sn1); *sn1 = tn; }
}

__device__ __forceinline__ void steqr2_01(float& dA, float& eA, float& dB,
                                          bool ql, EIGH_Z_PARAMS) {
  const float eps2 = 3.5527136788e-15f, safmin = 1.1754943508e-38f;
  float tst = eA * eA;
  float thr = ql ? (eps2 * fabsf(dA)) * fabsf(dB) + safmin
                 : (eps2 * fabsf(dB)) * fabsf(dA) + safmin;
  if (tst <= thr) { eA = 0.0f; return; }
  float rt1, rt2, c, s;
  slaev2_(dA, eA, dB, &rt1, &rt2, &c, &s);
  ROT01(c, s);
  dA = rt1; dB = rt2; eA = 0.0f;
}

__device__ __forceinline__ void steqr2_12(float& dA, float& eA, float& dB,
                                          bool ql, EIGH_Z_PARAMS) {
  const float eps2 = 3.5527136788e-15f, safmin = 1.1754943508e-38f;
  float tst = eA * eA;
  float thr = ql ? (eps2 * fabsf(dA)) * fabsf(dB) + safmin
                 : (eps2 * fabsf(dB)) * fabsf(dA) + safmin;
  if (tst <= thr) { eA = 0.0f; return; }
  float rt1, rt2, c, s;
  slaev2_(dA, eA, dB, &rt1, &rt2, &c, &s);
  ROT12(c, s);
  dA = rt1; dB = rt2; eA = 0.0f;
}

__device__ __forceinline__ void steqr_ql3(float& d1, float& d2, float& d3,
                                          float& e1, float& e2, int& jtot,
                                          EIGH_Z_PARAMS) {
  const float eps2 = 3.5527136788e-15f, safmin = 1.1754943508e-38f;
  int l = 1;
  while (true) {
    if (l == 1) {
      if (e1 * e1 <= (eps2 * fabsf(d1)) * fabsf(d2) + safmin) { e1 = 0.0f; l = 2; continue; }
      if (e2 * e2 <= (eps2 * fabsf(d2)) * fabsf(d3) + safmin) {
        e2 = 0.0f;
        float rt1, rt2, c, s;
        slaev2_(d1, e1, d2, &rt1, &rt2, &c, &s);
        ROT01(c, s);
        d1 = rt1; d2 = rt2; e1 = 0.0f;
        l = 3; continue;
      }
      if (jtot == 90) return;
      jtot++;
      float p = d1;
      float g = (d2 - p) / (2.0f * e1);
      float r = slapy2(g, 1.0f);
      g = d3 - p + (e1 / (g + f_sign(r, g)));
      float s = 1.0f, c = 1.0f; p = 0.0f;
      float f, b, wc1, wc2, ws1, ws2;
      f = s * e2; b = c * e2;
      slartg_(g, f, &c, &s, &r);
      g = d3 - p;
      r = (d2 - g) * s + 2.0f * c * b;
      p = s * r;
      d3 = g + p;
      g = c * r - b;
      wc2 = c; ws2 = -s;
      f = s * e1; b = c * e1;
      slartg_(g, f, &c, &s, &r);
      e2 = r;
      g = d2 - p;
      r = (d1 - g) * s + 2.0f * c * b;
      p = s * r;
      d2 = g + p;
      g = c * r - b;
      wc1 = c; ws1 = -s;
      if (wc2 != 1.0f || ws2 != 0.0f) ROT12(wc2, ws2);
      if (wc1 != 1.0f || ws1 != 0.0f) ROT01(wc1, ws1);
      d1 = d1 - p;
      e1 = g;
      continue;
    }
    if (l == 2) {
      if (e2 * e2 <= (eps2 * fabsf(d2)) * fabsf(d3) + safmin) { e2 = 0.0f; l = 3; continue; }
      float rt1, rt2, c, s;
      slaev2_(d2, e2, d3, &rt1, &rt2, &c, &s);
      ROT12(c, s);
      d2 = rt1; d3 = rt2; e2 = 0.0f;
      return;
    }
    return;
  }
}

__device__ __forceinline__ void steqr_qr3(float& d1, float& d2, float& d3,
                                          float& e1, float& e2, int& jtot,
                                          EIGH_Z_PARAMS) {
  const float eps2 = 3.5527136788e-15f, safmin = 1.1754943508e-38f;
  int l = 3;
  while (true) {
    if (l == 3) {
      if (e2 * e2 <= (eps2 * fabsf(d3)) * fabsf(d2) + safmin) { e2 = 0.0f; l = 2; continue; }
      if (e1 * e1 <= (eps2 * fabsf(d2)) * fabsf(d1) + safmin) {
        e1 = 0.0f;
        float rt1, rt2, c, s;
        slaev2_(d2, e2, d3, &rt1, &rt2, &c, &s);
        ROT12(c, s);
        d2 = rt1; d3 = rt2; e2 = 0.0f;
        l = 1; continue;
      }
      if (jtot == 90) return;
      jtot++;
      float p = d3;
      float g = (d2 - p) / (2.0f * e2);
      float r = slapy2(g, 1.0f);
      g = d1 - p + (e2 / (g + f_sign(r, g)));
      float s = 1.0f, c = 1.0f; p = 0.0f;
      float f, b, wc1, wc2, ws1, ws2;
      f = s * e1; b = c * e1;
      slartg_(g, f, &c, &s, &r);
      g = d1 - p;
      r = (d2 - g) * s + 2.0f * c * b;
      p = s * r;
      d1 = g + p;
      g = c * r - b;
      wc1 = c; ws1 = s;
      f = s * e2; b = c * e2;
      slartg_(g, f, &c, &s, &r);
      e1 = r;
      g = d2 - p;
      r = (d3 - g) * s + 2.0f * c * b;
      p = s * r;
      d2 = g + p;
      g = c * r - b;
      wc2 = c; ws2 = s;
      if (wc1 != 1.0f || ws1 != 0.0f) ROT01(wc1, ws1);
      if (wc2 != 1.0f || ws2 != 0.0f) ROT12(wc2, ws2);
      d3 = d3 - p;
      e2 = g;
      continue;
    }
    if (l == 2) {
      if (e1 * e1 <= (eps2 * fabsf(d2)) * fabsf(d1) + safmin) { e1 = 0.0f; l = 1; continue; }
      float rt1, rt2, c, s;
      slaev2_(d1, e1, d2, &rt1, &rt2, &c, &s);
      ROT01(c, s);
      d1 = rt1; d2 = rt2; e1 = 0.0f;
      return;
    }
    return;
  }
}

__device__ __forceinline__ void ssteqr3s(float& d1, float& d2, float& d3,
                                         float& e1, float& e2, EIGH_Z_PARAMS) {
  const float eps    = 5.9604644775e-08f;
  const float ssfmax = 3.0744573457e+18f;
  const float ssfmin = 3.0517578125e-05f;
  int jtot = 0;
  int m;
  {
    float tst = fabsf(e1);
    if (tst == 0.0f) m = 1;
    else if (tst <= (__fsqrt_rn(fabsf(d1)) * __fsqrt_rn(fabsf(d2))) * eps) { e1 = 0.0f; m = 1; }
    else {
      tst = fabsf(e2);
      if (tst == 0.0f) m = 2;
      else if (tst <= (__fsqrt_rn(fabsf(d2)) * __fsqrt_rn(fabsf(d3))) * eps) { e2 = 0.0f; m = 2; }
      else m = 3;
    }
  }
  if (m == 3) {
    float anorm = fmaxf(fmaxf(fabsf(d1), fabsf(d2)), fabsf(d3));
    anorm = fmaxf(anorm, fmaxf(fabsf(e1), fabsf(e2)));
    if (anorm != 0.0f) {
      int iscale = 0; float mul;
      if (anorm > ssfmax) {
        iscale = 1; mul = ssfmax / anorm;
        d1 *= mul; d2 *= mul; d3 *= mul; e1 *= mul; e2 *= mul;
      } else if (anorm < ssfmin) {
        iscale = 2; mul = ssfmin / anorm;
        d1 *= mul; d2 *= mul; d3 *= mul; e1 *= mul; e2 *= mul;
      }
      if (fabsf(d3) < fabsf(d1)) steqr_qr3(d1, d2, d3, e1, e2, jtot, EIGH_Z_ARGS);
      else                       steqr_ql3(d1, d2, d3, e1, e2, jtot, EIGH_Z_ARGS);
      if (iscale == 1) {
        mul = anorm / ssfmax;
        d1 *= mul; d2 *= mul; d3 *= mul; e1 *= mul; e2 *= mul;
      } else if (iscale == 2) {
        mul = anorm / ssfmin;
        d1 *= mul; d2 *= mul; d3 *= mul; e1 *= mul; e2 *= mul;
      }
    }
  } else if (m == 2) {
    float anorm = fmaxf(fmaxf(fabsf(d1), fabsf(d2)), fabsf(e1));
    if (anorm != 0.0f) {
      int iscale = 0; float mul;
      if (anorm > ssfmax) { iscale = 1; mul = ssfmax / anorm; d1 *= mul; d2 *= mul; e1 *= mul; }
      else if (anorm < ssfmin) { iscale = 2; mul = ssfmin / anorm; d1 *= mul; d2 *= mul; e1 *= mul; }
      steqr2_01(d1, e1, d2, !(fabsf(d2) < fabsf(d1)), EIGH_Z_ARGS);
      if (iscale == 1) { mul = anorm / ssfmax; d1 *= mul; d2 *= mul; e1 *= mul; }
      else if (iscale == 2) { mul = anorm / ssfmin; d1 *= mul; d2 *= mul; e1 *= mul; }
    }
  } else {
    int m2;
    float tst = fabsf(e2);
    if (tst == 0.0f) m2 = 2;
    else if (tst <= (__fsqrt_rn(fabsf(d2)) * __fsqrt_rn(fabsf(d3))) * eps) { e2 = 0.0f; m2 = 2; }
    else m2 = 3;
    if (m2 == 3) {
      float anorm = fmaxf(fmaxf(fabsf(d2), fabsf(d3)), fabsf(e2));
      if (anorm != 0.0f) {
        int iscale = 0; float mul;
        if (anorm > ssfmax) { iscale = 1; mul = ssfmax / anorm; d2 *= mul; d3 *= mul; e2 *= mul; }
        else if (anorm < ssfmin) { iscale = 2; mul = ssfmin / anorm; d2 *= mul; d3 *= mul; e2 *= mul; }
        steqr2_12(d2, e2, d3, !(fabsf(d3) < fabsf(d2)), EIGH_Z_ARGS);
        if (iscale == 1) { mul = anorm / ssfmax; d2 *= mul; d3 *= mul; e2 *= mul; }
        else if (iscale == 2) { mul = anorm / ssfmin; d2 *= mul; d3 *= mul; e2 *= mul; }
      }
    }
  }
  {
    int k = 1; float p = d1;
    if (d2 < p) { k = 2; p = d2; }
    if (d3 < p) { k = 3; p = d3; }
    if (k == 2)      { d2 = d1; d1 = p; SWAP01; }
    else if (k == 3) { d3 = d1; d1 = p; SWAP02; }
    if (d3 < d2) { p = d3; d3 = d2; d2 = p; SWAP12; }
  }
}

__device__ __forceinline__ void eigh3(float a11, float a21, float a31,
                                      float a22, float a32, float a33,
                                      EIGH_Z_PARAMS) {
  float tau1 = 0.0f, v3 = 0.0f, e1;
  float xnorm = fabsf(a31);
  if (xnorm == 0.0f) {
    tau1 = 0.0f;
    e1 = a21;
    v3 = 0.0f;
  } else {
    float beta = -f_sign(slapy2(a21, xnorm), a21);
    tau1 = (beta - a21) / beta;
    v3 = a31 / (a21 - beta);
    e1 = beta;
  }
  if (tau1 != 0.0f) {
    float x1 = tau1 * (a22 + a32 * v3);
    float x2 = tau1 * (a32 + a33 * v3);
    float alpha = -0.5f * tau1 * (x1 + x2 * v3);
    float w1 = x1 + alpha;
    float w2 = x2 + alpha * v3;
    a22 = a22 - w1 - w1;
    a32 = a32 - v3 * w1 - w2;
    a33 = a33 - v3 * w2 - w2 * v3;
  }
  float d1 = a11, d2 = a22, d3 = a33, e2 = a32;
  z00 = 1.0f; z01 = 0.0f; z02 = 0.0f;
  z10 = 0.0f; z11 = 1.0f; z12 = 0.0f;
  z20 = 0.0f; z21 = 0.0f; z22 = 1.0f;
  ssteqr3s(d1, d2, d3, e1, e2, EIGH_Z_ARGS);
  if (tau1 != 0.0f) {
    float tt;
    tt = z10 + v3 * z20; z10 -= tau1 * tt; z20 -= tau1 * tt * v3;
    tt = z11 + v3 * z21; z11 -= tau1 * tt; z21 -= tau1 * tt * v3;
    tt = z12 + v3 * z22; z12 -= tau1 * tt; z22 -= tau1 * tt * v3;
  }
}

// =============================== fused kernel ===============================
// 1 wave per center, 4 centers (waves) per block, grid = KTOT/4 blocks.
// Round-13 champion: global pos reads, coalesced phase-5, packed f32 math.

#define CE(i, j)                                                  \
  {                                                               \
    unsigned long long ta = K[i], tb = K[j];                      \
    bool sw = tb < ta;                                            \
    K[i] = sw ? tb : ta;                                          \
    K[j] = sw ? ta : tb;                                          \
  }

#define RFL(x) __int_as_float(__builtin_amdgcn_readfirstlane(__float_as_int(x)))

__global__ __launch_bounds__(256, 4) void dcconv_fused(
    const float* __restrict__ pos, const float* __restrict__ chan,
    const float* __restrict__ coeff, const float* __restrict__ bias,
    float* __restrict__ out) {
  const int t    = threadIdx.x;
  const int wv   = t >> 6;                 // 0..3 : center slot in block
  const int lane = t & 63;
  const int kglob = blockIdx.x * 4 + wv;   // global center id 0..4095
  const int sp   = kglob >> 8;             // space id
  const int ci   = kglob & 255;            // center within space
  const int base = sp * SPN;

  __shared__ __align__(16) float basis_sh[4][CONV][28];   // col 27 = 0
  __shared__ __align__(16) float feat_sh[4][CONV][INC];
  __shared__ __align__(16) float G4_sh[4][INC * NB];      // flat 864 per center

  // ---- phase 1: d2 for all 1024 points of this wave's space, in registers --
  const int cgl = base + ci * STRIDE;
  const float cx = pos[cgl * 3 + 0];
  const float cy = pos[cgl * 3 + 1];
  const float cz = pos[cgl * 3 + 2];

  unsigned long long K[16];
#pragma unroll
  for (int u = 0; u < 16; ++u) {
    const int j = u * 64 + lane;
    const float px = pos[(base + j) * 3 + 0];
    const float py = pos[(base + j) * 3 + 1];
    const float pz = pos[(base + j) * 3 + 2];
    float dx = __fsub_rn(cx, px), dy = __fsub_rn(cy, py), dz = __fsub_rn(cz, pz);
    float d2 = __fadd_rn(__fadd_rn(__fmul_rn(dx, dx), __fmul_rn(dy, dy)),
                         __fmul_rn(dz, dz));
    K[u] = (((unsigned long long)__float_as_uint(d2)) << 32) | (unsigned)j;
  }

  // ---- phase 1b: per-lane ascending sort (Batcher odd-even merge, 63 CEs) --
  CE(0, 1) CE(2, 3) CE(4, 5) CE(6, 7) CE(8, 9) CE(10, 11) CE(12, 13) CE(14, 15)
  CE(0, 2) CE(1, 3) CE(4, 6) CE(5, 7) CE(8, 10) CE(9, 11) CE(12, 14) CE(13, 15)
  CE(1, 2) CE(5, 6) CE(9, 10) CE(13, 14)
  CE(0, 4) CE(1, 5) CE(2, 6) CE(3, 7) CE(8, 12) CE(9, 13) CE(10, 14) CE(11, 15)
  CE(2, 4) CE(3, 5) CE(10, 12) CE(11, 13)
  CE(1, 2) CE(3, 4) CE(5, 6) CE(9, 10) CE(11, 12) CE(13, 14)
  CE(0, 8) CE(1, 9) CE(2, 10) CE(3, 11) CE(4, 12) CE(5, 13) CE(6, 14) CE(7, 15)
  CE(4, 8) CE(5, 9) CE(6, 10) CE(7, 11)
  CE(2, 4) CE(3, 5) CE(6, 8) CE(7, 9) CE(10, 12) CE(11, 13)
  CE(1, 2) CE(3, 4) CE(5, 6) CE(7, 8) CE(9, 10) CE(11, 12) CE(13, 14)

  // ---- phase 1c: 16 rounds of DPP wave-min + pop (set-exact selection) ----
  int myidx = cgl;   // lane c<16 will own neighbor c's global index
#pragma unroll 1
  for (int it = 0; it < CONV; ++it) {
    const float f0 = __uint_as_float((unsigned)(K[0] >> 32));  // NaN if empty
    const float m = wave_min64_bcast(f0);
    const unsigned long long msk = __ballot(f0 == m);
    const int wl = (int)__builtin_ctzll(msk);
    const int widx = __builtin_amdgcn_readlane((int)(unsigned)(K[0] & 0xffffffffu), wl);
    if (lane == it) myidx = base + widx;
    const bool on = (lane == wl);
#pragma unroll
    for (int u = 0; u < 15; ++u) K[u] = on ? K[u + 1] : K[u];
    K[15] = on ? ~0ull : K[15];
  }

  // ---- phase 2a: neighbor positions (lanes 0..15) ----
  float nx = 0.0f, ny = 0.0f, nz = 0.0f;
  if (lane < CONV) {
    const float* pp = pos + myidx * 3;
    nx = pp[0]; ny = pp[1]; nz = pp[2];
  }

  // ---- phase 3a (hoisted loads): feat values into named scalars ----
  const int hc = lane >> 5;          // 0/1
  const int ifeat = lane & 31;
  float fv0, fv1, fv2, fv3, fv4, fv5, fv6, fv7;
  {
    int g;
    g = __shfl(myidx,  0 + hc); fv0 = chan[g * INC + ifeat];
    g = __shfl(myidx,  2 + hc); fv1 = chan[g * INC + ifeat];
    g = __shfl(myidx,  4 + hc); fv2 = chan[g * INC + ifeat];
    g = __shfl(myidx,  6 + hc); fv3 = chan[g * INC + ifeat];
    g = __shfl(myidx,  8 + hc); fv4 = chan[g * INC + ifeat];
    g = __shfl(myidx, 10 + hc); fv5 = chan[g * INC + ifeat];
    g = __shfl(myidx, 12 + hc); fv6 = chan[g * INC + ifeat];
    g = __shfl(myidx, 14 + hc); fv7 = chan[g * INC + ifeat];
  }

  // ---- phase 2b: mean + cov via DPP sums (lanes>=16 contribute 0) ----
  const float mx = wave_sum64_bcast(nx) * 0.0625f;
  const float my = wave_sum64_bcast(ny) * 0.0625f;
  const float mz = wave_sum64_bcast(nz) * 0.0625f;
  if (lane == 0) {
    out[kglob * 3 + 0] = mx; out[kglob * 3 + 1] = my; out[kglob * 3 + 2] = mz;
  }
  const float lx = nx - mx, ly = ny - my, lz = nz - mz;   // valid lanes<16
  const float lxm = (lane < CONV) ? lx : 0.0f;
  const float lym = (lane < CONV) ? ly : 0.0f;
  const float lzm = (lane < CONV) ? lz : 0.0f;
  const float inv = 1.0f / (float)CONV;
  const float c00 = wave_sum64_bcast(lxm * lxm) * inv;
  const float c10 = wave_sum64_bcast(lym * lxm) * inv;
  const float c20 = wave_sum64_bcast(lzm * lxm) * inv;
  const float c11 = wave_sum64_bcast(lym * lym) * inv;
  const float c21 = wave_sum64_bcast(lzm * lym) * inv;
  const float c22 = wave_sum64_bcast(lzm * lzm) * inv;

  // ---- phase 2c: eigh on lane 0 ONLY, then readfirstlane broadcast of V ----
  float V00 = 0, V01 = 0, V02 = 0, V10 = 0, V11 = 0, V12 = 0,
        V20 = 0, V21 = 0, V22 = 0;
  if (lane == 0) {
    eigh3(c00, c10, c20, c11, c21, c22,
          V00, V01, V02, V10, V11, V12, V20, V21, V22);
  }
  V00 = RFL(V00); V01 = RFL(V01); V02 = RFL(V02);
  V10 = RFL(V10); V11 = RFL(V11); V12 = RFL(V12);
  V20 = RFL(V20); V21 = RFL(V21); V22 = RFL(V22);

  // ---- phase 2d: spherical coords + basis (lanes 0..15 of each wave) ----
  if (lane < CONV) {
    float x = lx * V00 + ly * V10 + lz * V20;
    float y = lx * V01 + ly * V11 + lz * V21;
    float z = lx * V02 + ly * V12 + lz * V22;
    float r = __fsqrt_rn(x * x + y * y + z * z + EPS_R);
    float ct = fminf(fmaxf(z / r, -1.0f), 1.0f);
    float theta = acosf(ct);
    float phi = atan2f(y, x);
    const float r1 = r, r2 = r * r;
    const float t1 = theta, t2 = theta * theta;
    const float p1 = phi, p2 = phi * phi;
    float4* bp = (float4*)(&basis_sh[wv][lane][0]);
    bp[0] = make_float4(1.0f,      p1,        p2,        t1);
    bp[1] = make_float4(t1 * p1,   t1 * p2,   t2,        t2 * p1);
    bp[2] = make_float4(t2 * p2,   r1,        r1 * p1,   r1 * p2);
    bp[3] = make_float4(r1 * t1,   r1 * t1 * p1, r1 * t1 * p2, r1 * t2);
    bp[4] = make_float4(r1 * t2 * p1, r1 * t2 * p2, r2,  r2 * p1);
    bp[5] = make_float4(r2 * p2,   r2 * t1,   r2 * t1 * p1, r2 * t1 * p2);
    bp[6] = make_float4(r2 * t2,   r2 * t2 * p1, r2 * t2 * p2, 0.0f);
  }

  // ---- phase 3b: feat -> LDS + resnet sum ----
  feat_sh[wv][ 0 + hc][ifeat] = fv0;
  feat_sh[wv][ 2 + hc][ifeat] = fv1;
  feat_sh[wv][ 4 + hc][ifeat] = fv2;
  feat_sh[wv][ 6 + hc][ifeat] = fv3;
  feat_sh[wv][ 8 + hc][ifeat] = fv4;
  feat_sh[wv][10 + hc][ifeat] = fv5;
  feat_sh[wv][12 + hc][ifeat] = fv6;
  feat_sh[wv][14 + hc][ifeat] = fv7;
  float s_loc = ((fv0 + fv1) + (fv2 + fv3)) + ((fv4 + fv5) + (fv6 + fv7));
  const float sres = wave_sum64_bcast(s_loc);
  if (lane < OUTC) out[OFF_RES + kglob * OUTC + lane] = sres;

  // ---- phase 4: G[i*27+j] = sum_c feat[c][i] * basis[c][j]  (packed f32,
  //      written to flat per-center LDS for phase 5's broadcast reads) ----
  {
    const int gi = lane >> 1;
    const int jh = lane & 1;
    const int jr0 = jh ? 12 : 0;       // 16B-aligned read start
    v2f a2[8];
#pragma unroll
    for (int q = 0; q < 8; ++q) a2[q] = (v2f)(0.0f);
#pragma unroll
    for (int c = 0; c < CONV; ++c) {
      const float f = feat_sh[wv][c][gi];
      const v2f f2 = (v2f)(f);
      const float4* bp = (const float4*)(&basis_sh[wv][c][jr0]);
#pragma unroll
      for (int q = 0; q < 4; ++q) {
        const float4 v4 = bp[q];
        v2f blo; blo.x = v4.x; blo.y = v4.y;
        v2f bhi; bhi.x = v4.z; bhi.y = v4.w;
        a2[2 * q + 0] += f2 * blo;
        a2[2 * q + 1] += f2 * bhi;
      }
    }
    float* gq = &G4_sh[wv][gi * NB];
    if (jh == 0) {   // j 0..13 from a2[0..6]
#pragma unroll
      for (int jj = 0; jj < 14; ++jj)
        gq[jj] = (jj & 1) ? a2[jj >> 1].y : a2[jj >> 1].x;
    } else {         // j 14..26 from a2[1..7] (m = j-12 in 2..14)
#pragma unroll
      for (int jj = 14; jj < 27; ++jj) {
        const int m = jj - 12;
        gq[jj] = (m & 1) ? a2[m >> 1].y : a2[m >> 1].x;
      }
    }
  }

  __syncthreads();   // all four centers' flat G visible

  // ---- phase 5 (coalesced): out[o][c] = sum_ij coeff[o][ij] * G[c][ij] ----
  // thread t = (o = t>>3, q = t&7); per k: lanes of same o read consecutive
  // float4s of coeff row o (coalesced); G reads are 8-addr + broadcast.
  {
    const int o = t >> 3;          // 0..31
    const int q = t & 7;           // 0..7
    const float4* arow = (const float4*)(coeff + o * (INC * NB));
    const float4* g0 = (const float4*)(&G4_sh[0][0]);
    const float4* g1 = (const float4*)(&G4_sh[1][0]);
    const float4* g2 = (const float4*)(&G4_sh[2][0]);
    const float4* g3 = (const float4*)(&G4_sh[3][0]);
    v2f ac0 = (v2f)(0.0f), ac1 = (v2f)(0.0f), ac2 = (v2f)(0.0f), ac3 = (v2f)(0.0f);
#pragma unroll 3
    for (int k = 0; k < 27; ++k) {
      const int f4 = k * 8 + q;
      const float4 A = arow[f4];
      v2f Alo; Alo.x = A.x; Alo.y = A.y;
      v2f Ahi; Ahi.x = A.z; Ahi.y = A.w;
      float4 Gv; v2f Glo, Ghi;
      Gv = g0[f4];
      Glo.x = Gv.x; Glo.y = Gv.y; Ghi.x = Gv.z; Ghi.y = Gv.w;
      ac0 += Alo * Glo; ac0 += Ahi * Ghi;
      Gv = g1[f4];
      Glo.x = Gv.x; Glo.y = Gv.y; Ghi.x = Gv.z; Ghi.y = Gv.w;
      ac1 += Alo * Glo; ac1 += Ahi * Ghi;
      Gv = g2[f4];
      Glo.x = Gv.x; Glo.y = Gv.y; Ghi.x = Gv.z; Ghi.y = Gv.w;
      ac2 += Alo * Glo; ac2 += Ahi * Ghi;
      Gv = g3[f4];
      Glo.x = Gv.x; Glo.y = Gv.y; Ghi.x = Gv.z; Ghi.y = Gv.w;
      ac3 += Alo * Glo; ac3 += Ahi * Ghi;
    }
    float s0 = ac0.x + ac0.y;
    float s1 = ac1.x + ac1.y;
    float s2 = ac2.x + ac2.y;
    float s3 = ac3.x + ac3.y;
    // reduce over the 8 q-lanes (row_shr 1,2,4); valid at q == 7
    s0 = group8_sum(s0); s1 = group8_sum(s1);
    s2 = group8_sum(s2); s3 = group8_sum(s3);
    if (q == 7) {
      const float b = bias[o];
      const int kb = blockIdx.x * 4;
      out[OFF_OUT + (kb + 0) * OUTC + o] = s0 + b;
      out[OFF_OUT + (kb + 1) * OUTC + o] = s1 + b;
      out[OFF_OUT + (kb + 2) * OUTC + o] = s2 + b;
      out[OFF_OUT + (kb + 3) * OUTC + o] = s3 + b;
    }
  }
}

extern "C" void kernel_launch(void* const* d_in, const int* in_sizes, int n_in,
                              void* d_out, int out_size, void* d_ws, size_t ws_size,
                              hipStream_t stream) {
  const float* pos   = (const float*)d_in[0];
  const float* chan  = (const float*)d_in[1];
  // d_in[2]=space_points_num, d_in[3]=outpoint_num: fixed (1024, 256) per setup
  const float* coeff = (const float*)d_in[4];
  const float* bias  = (const float*)d_in[5];
  float* out = (float*)d_out;
  dcconv_fused<<<dim3(KTOT / 4), dim3(256), 0, stream>>>(pos, chan, coeff, bias, out);
}